// Round 8
// baseline (355.774 us; speedup 1.0000x reference)
//
#include <hip/hip_runtime.h>
#include <hip/hip_bf16.h>

#define BATCH   256
#define NLAYERS 32
#define HID     1024
#define INTER   2816

typedef __attribute__((ext_vector_type(8))) short bf16x8;
typedef __attribute__((ext_vector_type(4))) float f32x4;
typedef __attribute__((ext_vector_type(4))) int   i32x4;

__device__ __forceinline__ ushort f2bf(float f) {
  __hip_bfloat16 b = __float2bfloat16(f);   // RNE
  return *reinterpret_cast<ushort*>(&b);
}

__device__ __forceinline__ bf16x8 cvt8(f32x4 a, f32x4 b) {
  bf16x8 o;
  o[0] = (short)f2bf(a[0]); o[1] = (short)f2bf(a[1]);
  o[2] = (short)f2bf(a[2]); o[3] = (short)f2bf(a[3]);
  o[4] = (short)f2bf(b[0]); o[5] = (short)f2bf(b[1]);
  o[6] = (short)f2bf(b[2]); o[7] = (short)f2bf(b[3]);
  return o;
}

// ---------------------------------------------------------------------------
// Kernel 0: h (b,n,d) fp32 -> Xp2 bf16, pre-swizzled + K-tiled (16 KB chunks
// per (layer,t)) so global_load_lds can write the LDS image linearly (G21).
// Per chunk: row b (256) x 4 granules(16B); slot f holds k-granule
// kg = f ^ ((b>>1)&3)  -> fragment ds_read_b128 is 2-way max (free).
// UNCHANGED from R6 (measured 0 bank conflicts).
// ---------------------------------------------------------------------------
__global__ __launch_bounds__(256) void k_pack(
    const float* __restrict__ h, ushort* __restrict__ Xp2) {
  const int pr    = blockIdx.x * 4 + (threadIdx.x >> 6);  // 0..8191
  const int b     = pr >> 5;
  const int layer = pr & 31;
  const int lane  = threadIdx.x & 63;
  const float* src = h + (size_t)b * (NLAYERS * HID) + (size_t)layer * HID;
  ushort* dstL = Xp2 + (size_t)layer * (32 * 8192);
#pragma unroll
  for (int c = 0; c < 2; ++c) {
    int gi = lane + c * 64;
    int t  = gi >> 2, kg = gi & 3;
    f32x4 v0 = *(const f32x4*)(src + t * 32 + kg * 8);
    f32x4 v1 = *(const f32x4*)(src + t * 32 + kg * 8 + 4);
    int f = kg ^ ((b >> 1) & 3);
    *(bf16x8*)(dstL + (size_t)t * 8192 + b * 32 + f * 8) = cvt8(v0, v1);
  }
}

// ---------------------------------------------------------------------------
// Kernel 1: act = silu(X Wg^T)*(X Wu^T).  BM=256, BN=32, BK=32, NK=32.
// Counted-vmcnt pipeline (T3/T4): ALL global traffic via global_load_lds;
// raw s_barriers; vmcnt never drained below 4 in the main loop.
//   step t: s_barrier                       (all waves done compute(t-1))
//           issue A(t+1)->Aslot[(t+1)&1]    (2 gload_lds/wave, Xp2 from L2)
//           issue B(t+2)->Bslot[(t+2)%3]    (1 gload_lds/wave, fp32 HBM)
//           s_waitcnt vmcnt(4)              (A(t),B(t) landed; 3 newer in flight)
//           s_barrier; sched_barrier(0)
//           compute(t): 4 A-frag b128 + 4 B b128(fp32)+cvt + 8 MFMA
// B LDS image: row r, 16B-granule slot f holds k-granule f^(r&7) — achieved
// by pre-swizzling the per-lane GLOBAL address (LDS dest linear, G21/m173).
// LDS 56 KB -> 2 blocks/CU.  T1 XCD swizzle: XCD x owns layers [4x,4x+4)
// -> Xp2 working set 2 MB < 4 MB L2 per XCD.
// ---------------------------------------------------------------------------
__global__ __launch_bounds__(512, 4) void k_gateup(
    const ushort* __restrict__ Xp2, const float* __restrict__ Wg,
    const float* __restrict__ Wu, ushort* __restrict__ act) {
  const int bid   = blockIdx.x;
  const int swz   = (bid & 7) * 352 + (bid >> 3);   // 2816 blocks, %8==0: bijective
  const int layer = swz / (INTER / 32);             // 88 itiles/layer
  const int it    = swz % (INTER / 32);
  const int i0    = it * 32;
  const int tid   = threadIdx.x;
  const int lane  = tid & 63;
  const int wave  = tid >> 6;
  const int wm    = wave >> 1;            // 0..3 : 64 batch rows
  const int wn    = wave & 1;             // 0..1 : 16 inter cols
  const int r16   = lane & 15;
  const int g4    = lane >> 4;

  __shared__ ushort Al[2][256 * 32];      // 2 x 16 KB bf16 (pre-swizzled image)
  __shared__ float  Bl[3][64 * 32];       // 3 x  8 KB fp32 (XOR-swizzled granules)

  f32x4 acc[4][2] = {};                   // [m][0=gate,1=up]

  // A staging: 2 instrs/wave, each 1 KB = 16 rows; linear copy of Xp2 chunk.
  const ushort* achunk = Xp2 + (size_t)layer * (32 * 8192);
  const int arow0 = wave * 32;            // rows [arow0, arow0+32)

  // B staging: 1 instr/wave = 8 rows x 128 B.  Lane l -> LDS row 8w+(l>>3),
  // slot l&7; global k-granule kg = (l&7) ^ ((l>>3)&7)  (XOR involution).
  const int brow = wave * 8 + (lane >> 3);            // tile row 0..63
  const int bkg  = (lane & 7) ^ ((lane >> 3) & 7);
  const float* bptr = (brow < 32 ? Wg + (size_t)(i0 + brow) * HID
                                 : Wu + (size_t)(i0 + brow - 32) * HID)
                      + (size_t)layer * INTER * HID + bkg * 4;

  // ---- prologue: A(0), B(0), B(1)
#pragma unroll
  for (int c = 0; c < 2; ++c)
    __builtin_amdgcn_global_load_lds(
        (const void*)(achunk + (arow0 + c * 16) * 32 + lane * 8),
        (void*)&Al[0][(arow0 + c * 16) * 32], 16, 0, 0);
  __builtin_amdgcn_global_load_lds((const void*)bptr,
                                   (void*)&Bl[0][wave * 256], 16, 0, 0);
  __builtin_amdgcn_global_load_lds((const void*)(bptr + 32),
                                   (void*)&Bl[1][wave * 256], 16, 0, 0);

  const int NK = HID / 32;                // 32
  for (int t = 0; t < NK; ++t) {
    __builtin_amdgcn_s_barrier();         // BARRIER-A: compute(t-1) done everywhere
    if (t + 1 < NK) {                     // A(t+1) -> slot (t+1)&1  (= slot of t-1, safe)
#pragma unroll
      for (int c = 0; c < 2; ++c)
        __builtin_amdgcn_global_load_lds(
            (const void*)(achunk + (size_t)(t + 1) * 8192 + (arow0 + c * 16) * 32 + lane * 8),
            (void*)&Al[(t + 1) & 1][(arow0 + c * 16) * 32], 16, 0, 0);
    }
    if (t + 2 < NK)                       // B(t+2) -> slot (t+2)%3 (= slot of t-1, safe)
      __builtin_amdgcn_global_load_lds(
          (const void*)(bptr + (t + 2) * 32),
          (void*)&Bl[(t + 2) % 3][wave * 256], 16, 0, 0);

    // counted drain: stage(t) complete; A(t+1),B(t+1),B(t+2) stay in flight
    if (t + 2 < NK)      asm volatile("s_waitcnt vmcnt(4)" ::: "memory");
    else if (t + 1 < NK) asm volatile("s_waitcnt vmcnt(3)" ::: "memory");
    else                 asm volatile("s_waitcnt vmcnt(0)" ::: "memory");
    __builtin_amdgcn_s_barrier();         // BARRIER-B: tile t visible to all
    __builtin_amdgcn_sched_barrier(0);

    const ushort* As = Al[t & 1];
    const float*  Bs = Bl[t % 3];

    bf16x8 af[4];
#pragma unroll
    for (int m = 0; m < 4; ++m) {
      int row = wm * 64 + m * 16 + r16;
      af[m] = *(bf16x8*)&As[row * 32 + ((g4 ^ ((row >> 1) & 3)) << 3)];
    }
    const int rg = wn * 16 + r16;         // gate row 0..31
    const int ru = 32 + rg;               // up   row 32..63
    f32x4 g0 = *(const f32x4*)&Bs[rg * 32 + (((2 * g4)     ^ (rg & 7)) << 2)];
    f32x4 g1 = *(const f32x4*)&Bs[rg * 32 + (((2 * g4 + 1) ^ (rg & 7)) << 2)];
    f32x4 u0 = *(const f32x4*)&Bs[ru * 32 + (((2 * g4)     ^ (ru & 7)) << 2)];
    f32x4 u1 = *(const f32x4*)&Bs[ru * 32 + (((2 * g4 + 1) ^ (ru & 7)) << 2)];
    bf16x8 bg = cvt8(g0, g1);
    bf16x8 bu = cvt8(u0, u1);
#pragma unroll
    for (int m = 0; m < 4; ++m) {
      acc[m][0] = __builtin_amdgcn_mfma_f32_16x16x32_bf16(af[m], bg, acc[m][0], 0, 0, 0);
      acc[m][1] = __builtin_amdgcn_mfma_f32_16x16x32_bf16(af[m], bu, acc[m][1], 0, 0, 0);
    }
  }

  // epilogue: silu(gate)*up, thread-local. C/D: col=lane&15, row=(lane>>4)*4+r
  const int r4 = (lane >> 4) * 4;
#pragma unroll
  for (int m = 0; m < 4; ++m)
#pragma unroll
    for (int r = 0; r < 4; ++r) {
      float g = acc[m][0][r];
      float u = acc[m][1][r];
      float a = (g / (1.f + __expf(-g))) * u;
      int b = wm * 64 + m * 16 + r4 + r;
      int i = i0 + wn * 16 + r16;
      act[((size_t)layer * BATCH + b) * INTER + i] = f2bf(a);
    }
}

// ---------------------------------------------------------------------------
// Kernel 2: out[b][layer][d] = act Wd^T.  UNCHANGED (measured ~65 us, at its
// HBM roofline: Wd 369 MB + out 32 MB; act reads served by L3).
// ---------------------------------------------------------------------------
#define BK 64

__global__ __launch_bounds__(512) void k_down(
    const ushort* __restrict__ act, const float* __restrict__ Wd,
    float* __restrict__ out) {
  const int bid   = blockIdx.x;
  const int layer = bid / (HID / 64);
  const int dtile = bid % (HID / 64);
  const int d0    = dtile * 64;
  const int tid   = threadIdx.x;
  const int lane  = tid & 63;
  const int wave  = tid >> 6;
  const int wm    = wave >> 1;
  const int wn    = wave & 1;

  __shared__ ushort lds[BATCH * BK + 64 * BK];       // 40 KiB
  ushort* Al = lds;
  ushort* Wl = lds + BATCH * BK;

  f32x4 acc[4][2] = {};

  int aldst[4];
  const ushort* asrc[4];
#pragma unroll
  for (int r = 0; r < 4; ++r) {
    int g = tid + 512 * r;
    int arow = g >> 3, akc = g & 7;
    aldst[r] = arow * BK + ((akc ^ (arow & 7)) << 3);
    asrc[r] = act + ((size_t)layer * BATCH + arow) * INTER + akc * 8;
  }
  const int wrow = tid >> 3, wkc = tid & 7;
  const int wldst = wrow * BK + ((wkc ^ (wrow & 7)) << 3);
  const float* wsrc = Wd + (size_t)layer * HID * INTER + (size_t)(d0 + wrow) * INTER + wkc * 8;

  i32x4 ra[4];
  f32x4 rw[2];

#pragma unroll
  for (int r = 0; r < 4; ++r) ra[r] = *(const i32x4*)asrc[r];
  rw[0] = *(const f32x4*)wsrc; rw[1] = *(const f32x4*)(wsrc + 4);

  const int NK = INTER / BK;   // 44
  for (int k = 0; k < NK; ++k) {
    __syncthreads();
#pragma unroll
    for (int r = 0; r < 4; ++r) *(i32x4*)&Al[aldst[r]] = ra[r];
    *(bf16x8*)&Wl[wldst] = cvt8(rw[0], rw[1]);
    __syncthreads();

    if (k + 1 < NK) {
      int off = (k + 1) * BK;
#pragma unroll
      for (int r = 0; r < 4; ++r) ra[r] = *(const i32x4*)(asrc[r] + off);
      rw[0] = *(const f32x4*)(wsrc + off); rw[1] = *(const f32x4*)(wsrc + off + 4);
    }

#pragma unroll
    for (int ks = 0; ks < 2; ++ks) {
      const int kg = ks * 4 + (lane >> 4);
      bf16x8 af[4];
#pragma unroll
      for (int m = 0; m < 4; ++m) {
        int row = wm * 64 + m * 16 + (lane & 15);
        af[m] = *(bf16x8*)&Al[row * BK + ((kg ^ (row & 7)) << 3)];
      }
#pragma unroll
      for (int n = 0; n < 2; ++n) {
        int row = wn * 32 + n * 16 + (lane & 15);
        bf16x8 bw = *(bf16x8*)&Wl[row * BK + ((kg ^ (row & 7)) << 3)];
#pragma unroll
        for (int m = 0; m < 4; ++m)
          acc[m][n] = __builtin_amdgcn_mfma_f32_16x16x32_bf16(af[m], bw, acc[m][n], 0, 0, 0);
      }
    }
  }

  const int c16 = lane & 15;
  const int r4  = (lane >> 4) * 4;
#pragma unroll
  for (int m = 0; m < 4; ++m)
#pragma unroll
    for (int n = 0; n < 2; ++n)
#pragma unroll
      for (int r = 0; r < 4; ++r) {
        int b = wm * 64 + m * 16 + r4 + r;
        int d = d0 + wn * 32 + n * 16 + c16;
        out[(size_t)b * (NLAYERS * HID) + (size_t)layer * HID + d] = acc[m][n][r];
      }
}

extern "C" void kernel_launch(void* const* d_in, const int* in_sizes, int n_in,
                              void* d_out, int out_size, void* d_ws, size_t ws_size,
                              hipStream_t stream) {
  const float* h  = (const float*)d_in[0];
  const float* Wg = (const float*)d_in[1];
  const float* Wu = (const float*)d_in[2];
  const float* Wd = (const float*)d_in[3];
  float* out  = (float*)d_out;
  ushort* act = (ushort*)d_ws;                                    // 46.1 MB
  ushort* Xp2 = (ushort*)d_ws + (size_t)NLAYERS * BATCH * INTER;  // +16.8 MB

  hipLaunchKernelGGL(k_pack, dim3(BATCH * NLAYERS / 4), dim3(256), 0, stream,
                     h, Xp2);
  hipLaunchKernelGGL(k_gateup, dim3(NLAYERS * (INTER / 32)), dim3(512), 0, stream,
                     Xp2, Wg, Wu, act);
  hipLaunchKernelGGL(k_down, dim3(NLAYERS * (HID / 64)), dim3(512), 0, stream,
                     act, Wd, out);
}

// Round 12
// 331.931 us; speedup vs baseline: 1.0718x; 1.0718x over previous
//
#include <hip/hip_runtime.h>
#include <hip/hip_bf16.h>

#define BATCH   256
#define NLAYERS 32
#define HID     1024
#define INTER   2816
#define BK      64

typedef __attribute__((ext_vector_type(8))) short bf16x8;
typedef __attribute__((ext_vector_type(4))) float f32x4;
typedef __attribute__((ext_vector_type(4))) int   i32x4;

__device__ __forceinline__ ushort f2bf(float f) {
  __hip_bfloat16 b = __float2bfloat16(f);   // RNE
  return *reinterpret_cast<ushort*>(&b);
}

__device__ __forceinline__ bf16x8 cvt8(f32x4 a, f32x4 b) {
  bf16x8 o;
  o[0] = (short)f2bf(a[0]); o[1] = (short)f2bf(a[1]);
  o[2] = (short)f2bf(a[2]); o[3] = (short)f2bf(a[3]);
  o[4] = (short)f2bf(b[0]); o[5] = (short)f2bf(b[1]);
  o[6] = (short)f2bf(b[2]); o[7] = (short)f2bf(b[3]);
  return o;
}

// ---------------------------------------------------------------------------
// Kernel 0: pack h (B,N,D) fp32 -> Xp[n][b][d] bf16 (contiguous per layer).
// ---------------------------------------------------------------------------
__global__ __launch_bounds__(256) void k_pack_v2(
    const float* __restrict__ h, ushort* __restrict__ Xp) {
  const int r    = blockIdx.x * 4 + (threadIdx.x >> 6);   // 0..8191 = b*32+n
  const int lane = threadIdx.x & 63;
  const int ro   = ((r & 31) * 256 + (r >> 5)) * 1024;    // out row = n*256+b
  const float* src = h + (size_t)r * 1024 + lane * 4;
  ushort* dst      = Xp + ro + lane * 4;
#pragma unroll
  for (int g = 0; g < 4; ++g) {
    f32x4 v = *(const f32x4*)(src + g * 256);
    ushort4 o;
    o.x = f2bf(v[0]); o.y = f2bf(v[1]); o.z = f2bf(v[2]); o.w = f2bf(v[3]);
    *(ushort4*)(dst + g * 256) = o;
  }
}

// ---------------------------------------------------------------------------
// Kernel 1: act[layer][b][i] = silu(X Wg^T) * (X Wu^T), bf16 -> ws.
// EXACT R4 structure (measured best: 230 us) + T1 XCD swizzle:
// swz = (bid%8)*352 + bid/8  (2816 blocks, %8==0 -> bijective).
// XCD x then owns layers [4x,4x+4): all its concurrent blocks share one
// layer's Xp slice (512 KB << 4 MB L2) -> the 1.44 GB A-restage traffic
// becomes XCD-local L2 hits instead of L3 round-trips.
// BM=256, BN=32, BK=64, 512 thr, 40 KB LDS, XOR swizzle (0 conflicts),
// 2 barriers/step, 1-deep register prefetch.  B-tile = 64 rows
// (0..31 Wg, 32..63 Wu); waves 8M x 1N; silu fused thread-locally.
// ---------------------------------------------------------------------------
__global__ __launch_bounds__(512) void k_gateup_v2(
    const ushort* __restrict__ Xp, const float* __restrict__ Wg,
    const float* __restrict__ Wu, ushort* __restrict__ act) {
  const int bid   = blockIdx.x;
  const int swz   = (bid & 7) * 352 + (bid >> 3);   // T1: XCD-contiguous
  const int layer = swz / (INTER / 32);    // 88 itiles/layer
  const int it    = swz % (INTER / 32);
  const int i0    = it * 32;
  const int tid   = threadIdx.x;
  const int lane  = tid & 63;
  const int wave  = tid >> 6;
  const int m0    = wave * 32;             // wave-exclusive 32 batch rows

  __shared__ ushort lds[BATCH * BK + 64 * BK];   // 40 KiB
  ushort* Al = lds;
  ushort* Wl = lds + BATCH * BK;

  f32x4 acc[2][4] = {};                    // [m][n]; n 0..1 gate, 2..3 up

  // A staging: 2048 granules of 8 bf16; 4 per thread (i32x4 copy, no cvt)
  int aldst[4];
  const ushort* asrc[4];
#pragma unroll
  for (int r = 0; r < 4; ++r) {
    int g = tid + 512 * r;
    int arow = g >> 3, akc = g & 7;
    aldst[r] = arow * BK + ((akc ^ (arow & 7)) << 3);
    asrc[r] = Xp + ((size_t)layer * BATCH + arow) * HID + akc * 8;
  }
  // B staging: row tid>>3 (0..63: <32 -> Wg, >=32 -> Wu), 8 floats at (tid&7)*8
  const int wrow = tid >> 3, wsl = tid & 7;
  const int wldst = wrow * BK + ((wsl ^ (wrow & 7)) << 3);
  const float* wsrc = (wrow < 32 ? Wg + (size_t)(i0 + wrow) * HID
                                 : Wu + (size_t)(i0 + wrow - 32) * HID) +
                      (size_t)layer * INTER * HID + wsl * 8;

  i32x4 ra[4];
  f32x4 rw[2];
#pragma unroll
  for (int r = 0; r < 4; ++r) ra[r] = *(const i32x4*)asrc[r];
  rw[0] = *(const f32x4*)wsrc; rw[1] = *(const f32x4*)(wsrc + 4);

  const int r16 = lane & 15;
  const int g4  = lane >> 4;

  const int NK = HID / BK;                 // 16
  for (int k = 0; k < NK; ++k) {
    __syncthreads();
#pragma unroll
    for (int r = 0; r < 4; ++r) *(i32x4*)&Al[aldst[r]] = ra[r];
    *(bf16x8*)&Wl[wldst] = cvt8(rw[0], rw[1]);
    __syncthreads();

    if (k + 1 < NK) {                      // prefetch t+1 (in flight across MFMA)
      int off = (k + 1) * BK;
#pragma unroll
      for (int r = 0; r < 4; ++r) ra[r] = *(const i32x4*)(asrc[r] + off);
      rw[0] = *(const f32x4*)(wsrc + off); rw[1] = *(const f32x4*)(wsrc + off + 4);
    }

#pragma unroll
    for (int ks = 0; ks < 2; ++ks) {
      const int kg = ks * 4 + g4;
      bf16x8 af[2];
#pragma unroll
      for (int m = 0; m < 2; ++m) {
        int row = m0 + m * 16 + r16;
        af[m] = *(bf16x8*)&Al[row * BK + ((kg ^ (row & 7)) << 3)];
      }
#pragma unroll
      for (int n = 0; n < 4; ++n) {
        int row = n * 16 + r16;
        bf16x8 bw = *(bf16x8*)&Wl[row * BK + ((kg ^ (row & 7)) << 3)];
#pragma unroll
        for (int m = 0; m < 2; ++m)
          acc[m][n] = __builtin_amdgcn_mfma_f32_16x16x32_bf16(af[m], bw, acc[m][n], 0, 0, 0);
      }
    }
  }

  // epilogue: silu(gate)*up, thread-local.  C/D: col=lane&15, row=(lane>>4)*4+r
  const int r4 = (lane >> 4) * 4;
#pragma unroll
  for (int m = 0; m < 2; ++m)
#pragma unroll
    for (int n = 0; n < 2; ++n)
#pragma unroll
      for (int r = 0; r < 4; ++r) {
        float g = acc[m][n][r];
        float u = acc[m][n + 2][r];
        float a = (g / (1.f + __expf(-g))) * u;
        int b = m0 + m * 16 + r4 + r;
        int i = i0 + n * 16 + r16;
        act[((size_t)layer * BATCH + b) * INTER + i] = f2bf(a);
      }
}

// ---------------------------------------------------------------------------
// Kernel 2: out[b][layer][d] = act Wd^T.  R1 structure (measured ~65 us)
// + T1 XCD swizzle (512 blocks, %8==0): XCD x owns layers [4x,4x+4) -> reads
// act written by the SAME XCD's k_gateup blocks (L2-local).
// ---------------------------------------------------------------------------
__global__ __launch_bounds__(512) void k_down_v2(
    const ushort* __restrict__ act, const float* __restrict__ Wd,
    float* __restrict__ out) {
  const int bid   = blockIdx.x;
  const int swz   = (bid & 7) * 64 + (bid >> 3);   // T1: XCD-contiguous
  const int layer = swz / (HID / 64);
  const int dtile = swz % (HID / 64);
  const int d0    = dtile * 64;
  const int tid   = threadIdx.x;
  const int lane  = tid & 63;
  const int wave  = tid >> 6;
  const int wm    = wave >> 1;
  const int wn    = wave & 1;

  __shared__ ushort lds[BATCH * BK + 64 * BK];       // 40 KiB
  ushort* Al = lds;
  ushort* Wl = lds + BATCH * BK;

  f32x4 acc[4][2] = {};

  int aldst[4];
  const ushort* asrc[4];
#pragma unroll
  for (int r = 0; r < 4; ++r) {
    int g = tid + 512 * r;
    int arow = g >> 3, akc = g & 7;
    aldst[r] = arow * BK + ((akc ^ (arow & 7)) << 3);
    asrc[r] = act + ((size_t)layer * BATCH + arow) * INTER + akc * 8;
  }
  const int wrow = tid >> 3, wkc = tid & 7;
  const int wldst = wrow * BK + ((wkc ^ (wrow & 7)) << 3);
  const float* wsrc = Wd + (size_t)layer * HID * INTER + (size_t)(d0 + wrow) * INTER + wkc * 8;

  i32x4 ra[4];
  f32x4 rw[2];

#pragma unroll
  for (int r = 0; r < 4; ++r) ra[r] = *(const i32x4*)asrc[r];
  rw[0] = *(const f32x4*)wsrc; rw[1] = *(const f32x4*)(wsrc + 4);

  const int NK = INTER / BK;   // 44
  for (int k = 0; k < NK; ++k) {
    __syncthreads();
#pragma unroll
    for (int r = 0; r < 4; ++r) *(i32x4*)&Al[aldst[r]] = ra[r];
    *(bf16x8*)&Wl[wldst] = cvt8(rw[0], rw[1]);
    __syncthreads();

    if (k + 1 < NK) {
      int off = (k + 1) * BK;
#pragma unroll
      for (int r = 0; r < 4; ++r) ra[r] = *(const i32x4*)(asrc[r] + off);
      rw[0] = *(const f32x4*)(wsrc + off); rw[1] = *(const f32x4*)(wsrc + off + 4);
    }

#pragma unroll
    for (int ks = 0; ks < 2; ++ks) {
      const int kg = ks * 4 + (lane >> 4);
      bf16x8 af[4];
#pragma unroll
      for (int m = 0; m < 4; ++m) {
        int row = wm * 64 + m * 16 + (lane & 15);
        af[m] = *(bf16x8*)&Al[row * BK + ((kg ^ (row & 7)) << 3)];
      }
#pragma unroll
      for (int n = 0; n < 2; ++n) {
        int row = wn * 32 + n * 16 + (lane & 15);
        bf16x8 bw = *(bf16x8*)&Wl[row * BK + ((kg ^ (row & 7)) << 3)];
#pragma unroll
        for (int m = 0; m < 4; ++m)
          acc[m][n] = __builtin_amdgcn_mfma_f32_16x16x32_bf16(af[m], bw, acc[m][n], 0, 0, 0);
      }
    }
  }

  const int c16 = lane & 15;
  const int r4  = (lane >> 4) * 4;
#pragma unroll
  for (int m = 0; m < 4; ++m)
#pragma unroll
    for (int n = 0; n < 2; ++n)
#pragma unroll
      for (int r = 0; r < 4; ++r) {
        int b = wm * 64 + m * 16 + r4 + r;
        int d = d0 + wn * 32 + n * 16 + c16;
        out[(size_t)b * (NLAYERS * HID) + (size_t)layer * HID + d] = acc[m][n][r];
      }
}

extern "C" void kernel_launch(void* const* d_in, const int* in_sizes, int n_in,
                              void* d_out, int out_size, void* d_ws, size_t ws_size,
                              hipStream_t stream) {
  const float* h  = (const float*)d_in[0];
  const float* Wg = (const float*)d_in[1];
  const float* Wu = (const float*)d_in[2];
  const float* Wd = (const float*)d_in[3];
  float* out  = (float*)d_out;
  ushort* act = (ushort*)d_ws;                                   // 46.1 MB
  ushort* Xp  = (ushort*)d_ws + (size_t)NLAYERS * BATCH * INTER; // +16.8 MB

  hipLaunchKernelGGL(k_pack_v2, dim3(BATCH * NLAYERS / 4), dim3(256), 0, stream,
                     h, Xp);
  hipLaunchKernelGGL(k_gateup_v2, dim3(NLAYERS * (INTER / 32)), dim3(512), 0, stream,
                     Xp, Wg, Wu, act);
  hipLaunchKernelGGL(k_down_v2, dim3(NLAYERS * (HID / 64)), dim3(512), 0, stream,
                     act, Wd, out);
}